// Round 3
// baseline (472.898 us; speedup 1.0000x reference)
//
#include <hip/hip_runtime.h>

#define BB 256
#define PP 48
#define NN 64
#define EPSBN 1e-5f

typedef __attribute__((ext_vector_type(8))) short bf16x8;
typedef __attribute__((ext_vector_type(4))) float f32x4;

// ---- LDS region offsets (ushort elements) ----
#define S1S 0        // [64][256] sender-half L1 pre-act     | N: fo1/fo2 (0..32767)
#define S1R 16384    // [64][256] receiver-half L1 + bias    | N: (high half of fo1/fo2)
#define XNT 32768    // [64][64]  xn (k 48..63 zero)
#define STG 36864    // [256][64] weight staging             | N: act1N [64][256]
#define W3R 53248    // [64][128] fr3                        | N: act2N [64][128]
#define A2W 61440    // [16][128] per-wave act2, x4 waves    | N: fo3 [64][128]
#define A0O 69632    // [64][128] node in: ebar 0..63, xn 64..111, 0 pad
#define LDSE 77824   // 155648 B

__device__ __forceinline__ ushort f2b(float f) {
    union { float f; unsigned u; } a; a.f = f;
    unsigned u = a.u + 0x7FFFu + ((a.u >> 16) & 1u);
    return (ushort)(u >> 16);
}
__device__ __forceinline__ float b2f(ushort s) {
    union { unsigned u; float f; } a; a.u = ((unsigned)s) << 16;
    return a.f;
}
__device__ __forceinline__ int sidx(int row, int k, int kpad) {
    return row * kpad + ((((k >> 3) ^ (row & 7)) << 3) | (k & 7));
}
__device__ __forceinline__ bf16x8 ldfrag(const ushort* buf, int row, int k, int kpad) {
    return *(const bf16x8*)(buf + row * kpad + (((k >> 3) ^ (row & 7)) << 3));
}
__device__ __forceinline__ f32x4 MFMA(bf16x8 a, bf16x8 b, f32x4 c) {
    return __builtin_amdgcn_mfma_f32_16x16x32_bf16(a, b, c, 0, 0, 0);
}
__device__ __forceinline__ void stAct(ushort* buf, int row, int c0, int kpad, f32x4 a, float4 bi) {
    ushort4 o;
    o.x = f2b(fmaxf(a[0] + bi.x, 0.f));
    o.y = f2b(fmaxf(a[1] + bi.y, 0.f));
    o.z = f2b(fmaxf(a[2] + bi.z, 0.f));
    o.w = f2b(fmaxf(a[3] + bi.w, 0.f));
    *(ushort4*)(buf + row * kpad + ((((c0 >> 3) ^ (row & 7)) << 3) | (c0 & 7))) = o;
}
__device__ __forceinline__ void stRaw(ushort* buf, int row, int c0, int kpad, f32x4 a, float4 bi) {
    ushort4 o;
    o.x = f2b(a[0] + bi.x);
    o.y = f2b(a[1] + bi.y);
    o.z = f2b(a[2] + bi.z);
    o.w = f2b(a[3] + bi.w);
    *(ushort4*)(buf + row * kpad + ((((c0 >> 3) ^ (row & 7)) << 3) | (c0 & 7))) = o;
}
// act1 fragment: relu(receiver-half + sender-half), elementwise in fp32, RNE pack
__device__ __forceinline__ bf16x8 addrelu8(bf16x8 a, bf16x8 b) {
    bf16x8 o;
#pragma unroll
    for (int j = 0; j < 8; ++j)
        o[j] = (short)f2b(fmaxf(b2f((ushort)a[j]) + b2f((ushort)b[j]), 0.f));
    return o;
}
__device__ __forceinline__ bf16x8 pk8(float4 a, float4 b) {
    bf16x8 r;
    r[0] = (short)f2b(a.x); r[1] = (short)f2b(a.y);
    r[2] = (short)f2b(a.z); r[3] = (short)f2b(a.w);
    r[4] = (short)f2b(b.x); r[5] = (short)f2b(b.y);
    r[6] = (short)f2b(b.z); r[7] = (short)f2b(b.w);
    return r;
}

// ---------------- batchnorm stats ----------------
__global__ __launch_bounds__(256) void bn_stats_kernel(
    const float* __restrict__ x, const float* __restrict__ gamma,
    const float* __restrict__ beta, float* __restrict__ scale, float* __restrict__ bias)
{
    __shared__ float s_sum[256], s_sq[256];
    int p = blockIdx.x, t = threadIdx.x;
    float sum = 0.f, sq = 0.f;
    for (int i = t; i < BB * NN; i += 256) {
        int b = i >> 6, n = i & 63;
        float v = x[b * PP * NN + p * NN + n];
        sum += v; sq += v * v;
    }
    s_sum[t] = sum; s_sq[t] = sq;
    __syncthreads();
    for (int off = 128; off > 0; off >>= 1) {
        if (t < off) { s_sum[t] += s_sum[t + off]; s_sq[t] += s_sq[t + off]; }
        __syncthreads();
    }
    if (t == 0) {
        float inv = 1.f / (float)(BB * NN);
        float mean = s_sum[0] * inv;
        float var  = s_sq[0] * inv - mean * mean;
        float sc   = gamma[p] * rsqrtf(var + EPSBN);
        scale[p] = sc;
        bias[p]  = beta[p] - mean * sc;
    }
}

// ---------------- mega kernel: one block per batch ----------------
__global__ __launch_bounds__(256, 1) void meg_kernel(
    const float* __restrict__ x,
    const float* __restrict__ scl, const float* __restrict__ bia,
    const float* __restrict__ fr1_w, const float* __restrict__ fr1_b,
    const float* __restrict__ fr2_w, const float* __restrict__ fr2_b,
    const float* __restrict__ fr3_w, const float* __restrict__ fr3_b,
    const float* __restrict__ fo1_w, const float* __restrict__ fo1_b,
    const float* __restrict__ fo2_w, const float* __restrict__ fo2_b,
    const float* __restrict__ fo3_w, const float* __restrict__ fo3_b,
    const float* __restrict__ fc1_w, const float* __restrict__ fc1_b,
    const float* __restrict__ fc2_w, const float* __restrict__ fc2_b,
    const float* __restrict__ fc3_w, const float* __restrict__ fc3_b,
    float* __restrict__ out)
{
    __shared__ __align__(16) ushort L[LDSE];
    __shared__ float biasR[256], bias2s[128], bias3s[64];
    __shared__ float red[64], h1[32], h2[16];

    int b = blockIdx.x, t = threadIdx.x;
    int w = t >> 6;
    int l = t & 63;
    int lx = l & 15;
    int lq = l >> 4;

    // ================= prologue =================
    // fr2 -> registers (full 128x256, per wave): a2[m][ks] = A[m*16+lx][ks*32+lq*8 ..+7]
    bf16x8 a2[8][8];
#pragma unroll
    for (int m = 0; m < 8; ++m)
#pragma unroll
        for (int ks = 0; ks < 8; ++ks) {
            const float* p = fr2_w + (m * 16 + lx) * 256 + ks * 32 + lq * 8;
            float4 f0 = *(const float4*)p;
            float4 f1 = *(const float4*)(p + 4);
            a2[m][ks] = pk8(f0, f1);
        }

    // xnT [64][64]
    for (int i = t; i < 4096; i += 256) {
        int n = i >> 6, k = i & 63;
        float v = (k < PP) ? x[b * PP * NN + k * NN + n] * scl[k] + bia[k] : 0.f;
        L[XNT + sidx(n, k, 64)] = f2b(v);
    }
    // A0: xn cols 64..111, zero elsewhere (ebar cols rewritten in phase E)
    for (int i = t; i < 8192; i += 256) {
        int n = i >> 7, k = i & 127;
        float v = 0.f;
        if (k >= 64 && k < 112) {
            int p = k - 64;
            v = x[b * PP * NN + p * NN + n] * scl[p] + bia[p];
        }
        L[A0O + sidx(n, k, 128)] = f2b(v);
    }
    // fr3 -> W3R [64][128]
    for (int i = t; i < 8192; i += 256) {
        int ch = i >> 7, k = i & 127;
        L[W3R + sidx(ch, k, 128)] = f2b(fr3_w[i]);
    }
    // fr1 receiver half -> STG [256][64]
    for (int i = t; i < 16384; i += 256) {
        int ch = i >> 6, k = i & 63;
        L[STG + sidx(ch, k, 64)] = f2b((k < PP) ? fr1_w[ch * 96 + k] : 0.f);
    }
    biasR[t] = fr1_b[t];
    if (t < 128) bias2s[t] = fr2_b[t];
    if (t < 64)  bias3s[t] = fr3_b[t];
    __syncthreads();

    // GEMM1: S1R[node][ch] = fr1R . xn + b1 (no relu)
    {
        f32x4 acc[4][4];
#pragma unroll
        for (int j = 0; j < 4; ++j)
#pragma unroll
            for (int nt = 0; nt < 4; ++nt) acc[j][nt] = (f32x4){0.f, 0.f, 0.f, 0.f};
#pragma unroll
        for (int ks = 0; ks < 2; ++ks) {
            bf16x8 Bf[4];
#pragma unroll
            for (int nt = 0; nt < 4; ++nt) Bf[nt] = ldfrag(L + XNT, nt * 16 + lx, ks * 32 + lq * 8, 64);
#pragma unroll
            for (int j = 0; j < 4; ++j) {
                bf16x8 Af = ldfrag(L + STG, (4 * w + j) * 16 + lx, ks * 32 + lq * 8, 64);
#pragma unroll
                for (int nt = 0; nt < 4; ++nt) acc[j][nt] = MFMA(Af, Bf[nt], acc[j][nt]);
            }
        }
#pragma unroll
        for (int j = 0; j < 4; ++j) {
            int ch0 = (4 * w + j) * 16 + lq * 4;
            float4 bi = *(const float4*)&biasR[ch0];
#pragma unroll
            for (int nt = 0; nt < 4; ++nt)
                stRaw(L + S1R, nt * 16 + lx, ch0, 256, acc[j][nt], bi);
        }
    }
    __syncthreads();
    // fr1 sender half -> STG
    for (int i = t; i < 16384; i += 256) {
        int ch = i >> 6, k = i & 63;
        L[STG + sidx(ch, k, 64)] = f2b((k < PP) ? fr1_w[ch * 96 + PP + k] : 0.f);
    }
    __syncthreads();
    // GEMM2: S1S[node][ch] = fr1S . xn (no bias, no relu)
    {
        f32x4 acc[4][4];
#pragma unroll
        for (int j = 0; j < 4; ++j)
#pragma unroll
            for (int nt = 0; nt < 4; ++nt) acc[j][nt] = (f32x4){0.f, 0.f, 0.f, 0.f};
#pragma unroll
        for (int ks = 0; ks < 2; ++ks) {
            bf16x8 Bf[4];
#pragma unroll
            for (int nt = 0; nt < 4; ++nt) Bf[nt] = ldfrag(L + XNT, nt * 16 + lx, ks * 32 + lq * 8, 64);
#pragma unroll
            for (int j = 0; j < 4; ++j) {
                bf16x8 Af = ldfrag(L + STG, (4 * w + j) * 16 + lx, ks * 32 + lq * 8, 64);
#pragma unroll
                for (int nt = 0; nt < 4; ++nt) acc[j][nt] = MFMA(Af, Bf[nt], acc[j][nt]);
            }
        }
        float4 zb = make_float4(0.f, 0.f, 0.f, 0.f);
#pragma unroll
        for (int j = 0; j < 4; ++j) {
            int ch0 = (4 * w + j) * 16 + lq * 4;
#pragma unroll
            for (int nt = 0; nt < 4; ++nt)
                stRaw(L + S1S, nt * 16 + lx, ch0, 256, acc[j][nt], zb);
        }
    }
    __syncthreads();

    // hoisted per-phase constants
    float4 b2c[8];
#pragma unroll
    for (int m = 0; m < 8; ++m) b2c[m] = *(const float4*)&bias2s[m * 16 + lq * 4];
    float b3c[4];
#pragma unroll
    for (int n3 = 0; n3 < 4; ++n3) b3c[n3] = bias3s[n3 * 16 + lx];

    // ================= phase E: 16 receivers per wave, no barriers =================
    ushort* a2w = L + A2W + w * 2048;   // wave-private [16][128]
#pragma unroll 1
    for (int i = 0; i < 16; ++i) {
        int r = w * 16 + i;
        bf16x8 s1rc[8];
#pragma unroll
        for (int ks = 0; ks < 8; ++ks) s1rc[ks] = ldfrag(L + S1R, r, ks * 32 + lq * 8, 256);
        float part[4] = {0.f, 0.f, 0.f, 0.f};

#pragma unroll 1
        for (int c = 0; c < 4; ++c) {
            int e = c * 16 + lx;                 // this lane's edge (B-operand col)
            int s = e + (e >= r); if (s > 63) s = 63;   // sender node (edge 63 = pad)

            // ---- L2: act2 = relu(fr2 . act1 + b2), act1 built on the fly
            f32x4 acc2[8];
#pragma unroll
            for (int m = 0; m < 8; ++m) acc2[m] = (f32x4){0.f, 0.f, 0.f, 0.f};
#pragma unroll
            for (int ks = 0; ks < 8; ++ks) {
                bf16x8 sf = ldfrag(L + S1S, s, ks * 32 + lq * 8, 256);
                bf16x8 bfr = addrelu8(s1rc[ks], sf);
#pragma unroll
                for (int m = 0; m < 8; ++m) acc2[m] = MFMA(a2[m][ks], bfr, acc2[m]);
            }
#pragma unroll
            for (int m = 0; m < 8; ++m)
                stAct(a2w, lx, m * 16 + lq * 4, 128, acc2[m], b2c[m]);

            // ---- L3 (transposed): D[e][ch3] = act2 . fr3^T
            f32x4 acc3[4];
#pragma unroll
            for (int n3 = 0; n3 < 4; ++n3) acc3[n3] = (f32x4){0.f, 0.f, 0.f, 0.f};
#pragma unroll
            for (int ks = 0; ks < 4; ++ks) {
                bf16x8 af = ldfrag(a2w, lx, ks * 32 + lq * 8, 128);
#pragma unroll
                for (int n3 = 0; n3 < 4; ++n3) {
                    bf16x8 bfw = ldfrag(L + W3R, n3 * 16 + lx, ks * 32 + lq * 8, 128);
                    acc3[n3] = MFMA(af, bfw, acc3[n3]);
                }
            }
            // rows of D are edges e = c*16 + lq*4 + reg; relu+bias then sum over e
#pragma unroll
            for (int n3 = 0; n3 < 4; ++n3) {
                float bv = b3c[n3];
                float ssum = fmaxf(acc3[n3][0] + bv, 0.f)
                           + fmaxf(acc3[n3][1] + bv, 0.f)
                           + fmaxf(acc3[n3][2] + bv, 0.f);
                float last = fmaxf(acc3[n3][3] + bv, 0.f);
                if (c == 3) last = (lq == 3) ? 0.f : last;   // mask pad edge 63
                part[n3] += ssum + last;
            }
        }
        // reduce over lq groups (lanes ^16, ^32); lane holds ch3 = n3*16+lx
#pragma unroll
        for (int n3 = 0; n3 < 4; ++n3) {
            part[n3] += __shfl_xor(part[n3], 16, 64);
            part[n3] += __shfl_xor(part[n3], 32, 64);
        }
        if (lq == 0) {
#pragma unroll
            for (int n3 = 0; n3 < 4; ++n3)
                L[A0O + sidx(r, n3 * 16 + lx, 128)] = f2b(part[n3]);
        }
    }
    __syncthreads();

    // ================= phase N =================
    // fo1 (perm cols: ebar 0..63 = fo1[48..111], xn 64..111 = fo1[0..47]) -> L[0..32767]
    for (int i = t; i < 32768; i += 256) {
        int ch = i >> 7, k = i & 127;
        float v = 0.f;
        if (k < 64)       v = fo1_w[ch * 112 + PP + k];
        else if (k < 112) v = fo1_w[ch * 112 + (k - 64)];
        L[sidx(ch, k, 128)] = f2b(v);
    }
    // fo3 -> A2W region [64][128]
    for (int i = t; i < 8192; i += 256) {
        int ch = i >> 7, k = i & 127;
        L[A2W + sidx(ch, k, 128)] = f2b(fo3_w[i]);
    }
    biasR[t] = fo1_b[t];
    if (t < 128) bias2s[t] = fo2_b[t];
    if (t < 64)  bias3s[t] = fo3_b[t];
    __syncthreads();

    // L1N: M=256, N=64, K=128
    {
        f32x4 accN[4][4];
#pragma unroll
        for (int j = 0; j < 4; ++j)
#pragma unroll
            for (int nt = 0; nt < 4; ++nt) accN[j][nt] = (f32x4){0.f, 0.f, 0.f, 0.f};
#pragma unroll
        for (int ks = 0; ks < 4; ++ks) {
            bf16x8 Bf[4];
#pragma unroll
            for (int nt = 0; nt < 4; ++nt) Bf[nt] = ldfrag(L + A0O, nt * 16 + lx, ks * 32 + lq * 8, 128);
#pragma unroll
            for (int j = 0; j < 4; ++j) {
                bf16x8 Af = ldfrag(L, (4 * w + j) * 16 + lx, ks * 32 + lq * 8, 128);
#pragma unroll
                for (int nt = 0; nt < 4; ++nt) accN[j][nt] = MFMA(Af, Bf[nt], accN[j][nt]);
            }
        }
        __syncthreads();   // fo1 reads done
        // act1N -> STG [64][256]; stage fo2 -> L[0..32767]
#pragma unroll
        for (int j = 0; j < 4; ++j) {
            int ch0 = (4 * w + j) * 16 + lq * 4;
            float4 bi = *(const float4*)&biasR[ch0];
#pragma unroll
            for (int nt = 0; nt < 4; ++nt)
                stAct(L + STG, nt * 16 + lx, ch0, 256, accN[j][nt], bi);
        }
    }
    for (int i = t; i < 32768; i += 256) {
        int ch = i >> 8, k = i & 255;
        L[sidx(ch, k, 256)] = f2b(fo2_w[i]);
    }
    __syncthreads();

    // L2N: M=128, N=64, K=256 -> act2N @ W3R [64][128]
    {
        f32x4 acc2N[2][4];
#pragma unroll
        for (int j = 0; j < 2; ++j)
#pragma unroll
            for (int nt = 0; nt < 4; ++nt) acc2N[j][nt] = (f32x4){0.f, 0.f, 0.f, 0.f};
#pragma unroll
        for (int ks = 0; ks < 8; ++ks) {
            bf16x8 Bf[4];
#pragma unroll
            for (int nt = 0; nt < 4; ++nt) Bf[nt] = ldfrag(L + STG, nt * 16 + lx, ks * 32 + lq * 8, 256);
#pragma unroll
            for (int j = 0; j < 2; ++j) {
                bf16x8 Af = ldfrag(L, (2 * w + j) * 16 + lx, ks * 32 + lq * 8, 256);
#pragma unroll
                for (int nt = 0; nt < 4; ++nt) acc2N[j][nt] = MFMA(Af, Bf[nt], acc2N[j][nt]);
            }
        }
#pragma unroll
        for (int j = 0; j < 2; ++j) {
            int ch0 = (2 * w + j) * 16 + lq * 4;
            float4 bi = *(const float4*)&bias2s[ch0];
#pragma unroll
            for (int nt = 0; nt < 4; ++nt)
                stAct(L + W3R, nt * 16 + lx, ch0, 128, acc2N[j][nt], bi);
        }
    }
    __syncthreads();

    // L3N: M=64, N=64, K=128; relu+bias, sum over nodes
    {
        f32x4 acc3N[4];
#pragma unroll
        for (int nt = 0; nt < 4; ++nt) acc3N[nt] = (f32x4){0.f, 0.f, 0.f, 0.f};
#pragma unroll
        for (int ks = 0; ks < 4; ++ks) {
            bf16x8 Af = ldfrag(L + A2W, 16 * w + lx, ks * 32 + lq * 8, 128);
#pragma unroll
            for (int nt = 0; nt < 4; ++nt) {
                bf16x8 Bf = ldfrag(L + W3R, nt * 16 + lx, ks * 32 + lq * 8, 128);
                acc3N[nt] = MFMA(Af, Bf, acc3N[nt]);
            }
        }
        float4 b3 = *(const float4*)&bias3s[16 * w + lq * 4];
        float o0 = 0.f, o1 = 0.f, o2 = 0.f, o3 = 0.f;
#pragma unroll
        for (int nt = 0; nt < 4; ++nt) {
            o0 += fmaxf(acc3N[nt][0] + b3.x, 0.f);
            o1 += fmaxf(acc3N[nt][1] + b3.y, 0.f);
            o2 += fmaxf(acc3N[nt][2] + b3.z, 0.f);
            o3 += fmaxf(acc3N[nt][3] + b3.w, 0.f);
        }
#pragma unroll
        for (int off = 8; off >= 1; off >>= 1) {
            o0 += __shfl_xor(o0, off, 16);
            o1 += __shfl_xor(o1, off, 16);
            o2 += __shfl_xor(o2, off, 16);
            o3 += __shfl_xor(o3, off, 16);
        }
        if (lx == 0) {
            int ch0 = 16 * w + lq * 4;
            *(float4*)&red[ch0] = make_float4(o0, o1, o2, o3);
        }
    }
    __syncthreads();

    if (t < 25) {
        float s = fc1_b[t];
        for (int k = 0; k < 64; ++k) s += fc1_w[t * 64 + k] * red[k];
        h1[t] = s;
    }
    __syncthreads();
    if (t < 15) {
        float s = fc2_b[t];
        for (int k = 0; k < 25; ++k) s += fc2_w[t * 25 + k] * h1[k];
        h2[t] = s;
    }
    __syncthreads();
    if (t < 5) {
        float s = fc3_b[t];
        for (int k = 0; k < 15; ++k) s += fc3_w[t * 15 + k] * h2[k];
        out[b * 5 + t] = s;
    }
}

extern "C" void kernel_launch(void* const* d_in, const int* in_sizes, int n_in,
                              void* d_out, int out_size, void* d_ws, size_t ws_size,
                              hipStream_t stream)
{
    const float* x        = (const float*)d_in[0];
    const float* bn_gamma = (const float*)d_in[3];
    const float* bn_beta  = (const float*)d_in[4];
    const float* fr1_w = (const float*)d_in[5];
    const float* fr1_b = (const float*)d_in[6];
    const float* fr2_w = (const float*)d_in[7];
    const float* fr2_b = (const float*)d_in[8];
    const float* fr3_w = (const float*)d_in[9];
    const float* fr3_b = (const float*)d_in[10];
    const float* fo1_w = (const float*)d_in[11];
    const float* fo1_b = (const float*)d_in[12];
    const float* fo2_w = (const float*)d_in[13];
    const float* fo2_b = (const float*)d_in[14];
    const float* fo3_w = (const float*)d_in[15];
    const float* fo3_b = (const float*)d_in[16];
    const float* fc1_w = (const float*)d_in[17];
    const float* fc1_b = (const float*)d_in[18];
    const float* fc2_w = (const float*)d_in[19];
    const float* fc2_b = (const float*)d_in[20];
    const float* fc3_w = (const float*)d_in[21];
    const float* fc3_b = (const float*)d_in[22];

    float* ws    = (float*)d_ws;
    float* scale = ws;
    float* bias  = ws + 64;
    float* out   = (float*)d_out;

    bn_stats_kernel<<<dim3(PP), dim3(256), 0, stream>>>(x, bn_gamma, bn_beta, scale, bias);
    meg_kernel<<<dim3(BB), dim3(256), 0, stream>>>(
        x, scale, bias,
        fr1_w, fr1_b, fr2_w, fr2_b, fr3_w, fr3_b,
        fo1_w, fo1_b, fo2_w, fo2_b, fo3_w, fo3_b,
        fc1_w, fc1_b, fc2_w, fc2_b, fc3_w, fc3_b, out);
}

// Round 4
// 377.578 us; speedup vs baseline: 1.2525x; 1.2525x over previous
//
#include <hip/hip_runtime.h>
#include <hip/hip_bf16.h>

#define BB 256
#define PP 48
#define NN 64
#define EPSBN 1e-5f

typedef __attribute__((ext_vector_type(8))) short bf16x8;
typedef __attribute__((ext_vector_type(4))) float f32x4;

// ---- LDS regions (ushort offsets), total 77824 ushorts = 155648 B ----
#define BIGO 0       // 32768: fr1R/[+16384]fr1S staging -> fr2 [128][256] | N: fo1 [256][128], fo2 [128][256]
#define S1SO 32768   // 16384: S1S [64][256]                               | N: act1N [64][256]
#define S1RO 49152   // 16384: S1R [64][256]; cols 0..63 overwritten w/ ebar| N: fo3 [64][128]
#define XNTO 65536   //  4096: xnT [64][64]                                | N: red/h1/h2 (floats)
#define A2WO 69632   //  8192: per-wave act2 [16][128] x4                  | N: act2N [64][128]
#define LDSE 77824

union U8 { bf16x8 v; unsigned u[4]; };

__device__ __forceinline__ unsigned pku(float a, float b) {
    union { __hip_bfloat162 h; unsigned u; } cv;
    cv.h = __float22bfloat162_rn(make_float2(a, b));
    return cv.u;
}
__device__ __forceinline__ ushort f2b(float f) {
    union { float f; unsigned u; } a; a.f = f;
    unsigned u = a.u + 0x7FFFu + ((a.u >> 16) & 1u);
    return (ushort)(u >> 16);
}
__device__ __forceinline__ float loF(unsigned u) { union { unsigned x; float f; } c; c.x = u << 16; return c.f; }
__device__ __forceinline__ float hiF(unsigned u) { union { unsigned x; float f; } c; c.x = u & 0xffff0000u; return c.f; }

__device__ __forceinline__ int sidx(int row, int k, int kpad) {
    return row * kpad + ((((k >> 3) ^ (row & 7)) << 3) | (k & 7));
}
__device__ __forceinline__ bf16x8 ldfrag(const ushort* buf, int row, int k, int kpad) {
    return *(const bf16x8*)(buf + row * kpad + (((k >> 3) ^ (row & 7)) << 3));
}
__device__ __forceinline__ f32x4 MFMA(bf16x8 a, bf16x8 b, f32x4 c) {
    return __builtin_amdgcn_mfma_f32_16x16x32_bf16(a, b, c, 0, 0, 0);
}
__device__ __forceinline__ void stAct(ushort* buf, int row, int c0, int kpad, f32x4 a, float4 bi) {
    uint2 o;
    o.x = pku(fmaxf(a[0] + bi.x, 0.f), fmaxf(a[1] + bi.y, 0.f));
    o.y = pku(fmaxf(a[2] + bi.z, 0.f), fmaxf(a[3] + bi.w, 0.f));
    *(uint2*)(buf + row * kpad + ((((c0 >> 3) ^ (row & 7)) << 3) | (c0 & 7))) = o;
}
__device__ __forceinline__ void stRaw(ushort* buf, int row, int c0, int kpad, f32x4 a, float4 bi) {
    uint2 o;
    o.x = pku(a[0] + bi.x, a[1] + bi.y);
    o.y = pku(a[2] + bi.z, a[3] + bi.w);
    *(uint2*)(buf + row * kpad + ((((c0 >> 3) ^ (row & 7)) << 3) | (c0 & 7))) = o;
}

// ---------------- batchnorm stats ----------------
__global__ __launch_bounds__(256) void bn_stats_kernel(
    const float* __restrict__ x, const float* __restrict__ gamma,
    const float* __restrict__ beta, float* __restrict__ scale, float* __restrict__ bias)
{
    __shared__ float s_sum[256], s_sq[256];
    int p = blockIdx.x, t = threadIdx.x;
    float sum = 0.f, sq = 0.f;
    for (int i = t; i < BB * NN; i += 256) {
        int b = i >> 6, n = i & 63;
        float v = x[b * PP * NN + p * NN + n];
        sum += v; sq += v * v;
    }
    s_sum[t] = sum; s_sq[t] = sq;
    __syncthreads();
    for (int off = 128; off > 0; off >>= 1) {
        if (t < off) { s_sum[t] += s_sum[t + off]; s_sq[t] += s_sq[t + off]; }
        __syncthreads();
    }
    if (t == 0) {
        float inv = 1.f / (float)(BB * NN);
        float mean = s_sum[0] * inv;
        float var  = s_sq[0] * inv - mean * mean;
        float sc   = gamma[p] * rsqrtf(var + EPSBN);
        scale[p] = sc;
        bias[p]  = beta[p] - mean * sc;
    }
}

// ---------------- mega kernel: one block per batch ----------------
__global__ __launch_bounds__(256, 1) void meg_kernel(
    const float* __restrict__ x,
    const float* __restrict__ scl, const float* __restrict__ bia,
    const float* __restrict__ fr1_w, const float* __restrict__ fr1_b,
    const float* __restrict__ fr2_w, const float* __restrict__ fr2_b,
    const float* __restrict__ fr3_w, const float* __restrict__ fr3_b,
    const float* __restrict__ fo1_w, const float* __restrict__ fo1_b,
    const float* __restrict__ fo2_w, const float* __restrict__ fo2_b,
    const float* __restrict__ fo3_w, const float* __restrict__ fo3_b,
    const float* __restrict__ fc1_w, const float* __restrict__ fc1_b,
    const float* __restrict__ fc2_w, const float* __restrict__ fc2_b,
    const float* __restrict__ fc3_w, const float* __restrict__ fc3_b,
    float* __restrict__ out)
{
    __shared__ __align__(16) ushort L[LDSE];

    int b = blockIdx.x, t = threadIdx.x;
    int w = t >> 6, l = t & 63, lx = l & 15, lq = l >> 4;

    // ---- xnT [64][64] (cols 48..63 zero)
    for (int i = t; i < 4096; i += 256) {
        int n = i >> 6, k = i & 63;
        float v = (k < PP) ? x[b * PP * NN + k * NN + n] * scl[k] + bia[k] : 0.f;
        L[XNTO + sidx(n, k, 64)] = f2b(v);
    }
    // ---- fr1 receiver half / sender half staged side by side in BIG
    for (int i = t; i < 16384; i += 256) {
        int ch = i >> 6, k = i & 63;
        L[BIGO + sidx(ch, k, 64)]         = f2b((k < PP) ? fr1_w[ch * 96 + k] : 0.f);
        L[BIGO + 16384 + sidx(ch, k, 64)] = f2b((k < PP) ? fr1_w[ch * 96 + PP + k] : 0.f);
    }
    __syncthreads();

    // ---- GEMM1+2 fused: S1R = fr1R.xn + b1, S1S = fr1S.xn
    {
        f32x4 aR[4][4], aS[4][4];
#pragma unroll
        for (int j = 0; j < 4; ++j)
#pragma unroll
            for (int nt = 0; nt < 4; ++nt) { aR[j][nt] = (f32x4){0.f,0.f,0.f,0.f}; aS[j][nt] = (f32x4){0.f,0.f,0.f,0.f}; }
#pragma unroll
        for (int ks = 0; ks < 2; ++ks) {
            bf16x8 Bf[4];
#pragma unroll
            for (int nt = 0; nt < 4; ++nt) Bf[nt] = ldfrag(L + XNTO, nt * 16 + lx, ks * 32 + lq * 8, 64);
#pragma unroll
            for (int j = 0; j < 4; ++j) {
                bf16x8 AfR = ldfrag(L + BIGO,        (4 * w + j) * 16 + lx, ks * 32 + lq * 8, 64);
                bf16x8 AfS = ldfrag(L + BIGO + 16384,(4 * w + j) * 16 + lx, ks * 32 + lq * 8, 64);
#pragma unroll
                for (int nt = 0; nt < 4; ++nt) {
                    aR[j][nt] = MFMA(AfR, Bf[nt], aR[j][nt]);
                    aS[j][nt] = MFMA(AfS, Bf[nt], aS[j][nt]);
                }
            }
        }
        __syncthreads();   // BIG reads done; safe to restage fr2 below
#pragma unroll
        for (int j = 0; j < 4; ++j) {
            int ch0 = (4 * w + j) * 16 + lq * 4;
            float4 bi = *(const float4*)(fr1_b + ch0);
            float4 zb = make_float4(0.f, 0.f, 0.f, 0.f);
#pragma unroll
            for (int nt = 0; nt < 4; ++nt) {
                stRaw(L + S1RO, nt * 16 + lx, ch0, 256, aR[j][nt], bi);
                stRaw(L + S1SO, nt * 16 + lx, ch0, 256, aS[j][nt], zb);
            }
        }
    }
    // ---- stage fr2 [128][256] into BIG (paired cvt_pk)
    for (int i = t; i < 16384; i += 256) {
        int ch = i >> 7, k2 = (i & 127) * 2;
        float2 v = *(const float2*)(fr2_w + ch * 256 + k2);
        *(unsigned*)(L + BIGO + sidx(ch, k2, 256)) = pku(v.x, v.y);
    }
    // ---- hoist fr3 to registers (B-operand, transposed L3), biases to regs
    bf16x8 bfw[4][4];
#pragma unroll
    for (int n3 = 0; n3 < 4; ++n3)
#pragma unroll
        for (int ks3 = 0; ks3 < 4; ++ks3) {
            const float* p = fr3_w + (n3 * 16 + lx) * 128 + ks3 * 32 + lq * 8;
            float4 f0 = *(const float4*)p;
            float4 f1 = *(const float4*)(p + 4);
            U8 g;
            g.u[0] = pku(f0.x, f0.y); g.u[1] = pku(f0.z, f0.w);
            g.u[2] = pku(f1.x, f1.y); g.u[3] = pku(f1.z, f1.w);
            bfw[n3][ks3] = g.v;
        }
    float4 b2c[8];
#pragma unroll
    for (int m = 0; m < 8; ++m) b2c[m] = *(const float4*)(fr2_b + m * 16 + lq * 4);
    float b3c[4];
#pragma unroll
    for (int n3 = 0; n3 < 4; ++n3) b3c[n3] = fr3_b[n3 * 16 + lx];
    __syncthreads();

    // ================= phase E: 16 receivers per wave, zero barriers =================
    ushort* a2w = L + A2WO + w * 2048;     // wave-private [16][128]
#pragma unroll 1
    for (int i = 0; i < 16; ++i) {
        int r = w * 16 + i;
        // this receiver's L1 pre-act (incl bias), unpacked to fp32
        float s1rf[64];
#pragma unroll
        for (int ks = 0; ks < 8; ++ks) {
            U8 f; f.v = ldfrag(L + S1RO, r, ks * 32 + lq * 8, 256);
#pragma unroll
            for (int jj = 0; jj < 4; ++jj) {
                s1rf[ks * 8 + 2 * jj]     = loF(f.u[jj]);
                s1rf[ks * 8 + 2 * jj + 1] = hiF(f.u[jj]);
            }
        }
        float part[4] = {0.f, 0.f, 0.f, 0.f};
#pragma unroll 1
        for (int p = 0; p < 2; ++p) {
            int eA = p * 32 + lx, eB = eA + 16;
            int sA = eA + (eA >= r);
            int sB = eB + (eB >= r); if (sB > 63) sB = 63;   // pad edge 63

            f32x4 acc2[8][2];
#pragma unroll
            for (int m = 0; m < 8; ++m) { acc2[m][0] = (f32x4){0.f,0.f,0.f,0.f}; acc2[m][1] = (f32x4){0.f,0.f,0.f,0.f}; }
#pragma unroll
            for (int ks = 0; ks < 8; ++ks) {
                U8 fa, fb;
                fa.v = ldfrag(L + S1SO, sA, ks * 32 + lq * 8, 256);
                fb.v = ldfrag(L + S1SO, sB, ks * 32 + lq * 8, 256);
                U8 bA, bB;
#pragma unroll
                for (int jj = 0; jj < 4; ++jj) {
                    float r0 = s1rf[ks * 8 + 2 * jj], r1 = s1rf[ks * 8 + 2 * jj + 1];
                    bA.u[jj] = pku(fmaxf(r0 + loF(fa.u[jj]), 0.f), fmaxf(r1 + hiF(fa.u[jj]), 0.f));
                    bB.u[jj] = pku(fmaxf(r0 + loF(fb.u[jj]), 0.f), fmaxf(r1 + hiF(fb.u[jj]), 0.f));
                }
#pragma unroll
                for (int m = 0; m < 8; ++m) {
                    bf16x8 Af = ldfrag(L + BIGO, m * 16 + lx, ks * 32 + lq * 8, 256);
                    acc2[m][0] = MFMA(Af, bA.v, acc2[m][0]);
                    acc2[m][1] = MFMA(Af, bB.v, acc2[m][1]);
                }
            }
#pragma unroll
            for (int cc = 0; cc < 2; ++cc) {
#pragma unroll
                for (int m = 0; m < 8; ++m)
                    stAct(a2w, lx, m * 16 + lq * 4, 128, acc2[m][cc], b2c[m]);
                f32x4 acc3[4];
#pragma unroll
                for (int n3 = 0; n3 < 4; ++n3) acc3[n3] = (f32x4){0.f,0.f,0.f,0.f};
#pragma unroll
                for (int ks3 = 0; ks3 < 4; ++ks3) {
                    bf16x8 af = ldfrag(a2w, lx, ks3 * 32 + lq * 8, 128);
#pragma unroll
                    for (int n3 = 0; n3 < 4; ++n3) acc3[n3] = MFMA(af, bfw[n3][ks3], acc3[n3]);
                }
                bool mpad = (p == 1) && (cc == 1) && (lq == 3);
#pragma unroll
                for (int n3 = 0; n3 < 4; ++n3) {
                    float bv = b3c[n3];
                    float s = fmaxf(acc3[n3][0] + bv, 0.f) + fmaxf(acc3[n3][1] + bv, 0.f)
                            + fmaxf(acc3[n3][2] + bv, 0.f);
                    float s3 = fmaxf(acc3[n3][3] + bv, 0.f);
                    part[n3] += s + (mpad ? 0.f : s3);
                }
            }
        }
#pragma unroll
        for (int n3 = 0; n3 < 4; ++n3) {
            part[n3] += __shfl_xor(part[n3], 16, 64);
            part[n3] += __shfl_xor(part[n3], 32, 64);
        }
        // S1R row r is dead now: deposit ebar[r][ch] into its cols 0..63
        if (lq == 0) {
#pragma unroll
            for (int n3 = 0; n3 < 4; ++n3)
                L[S1RO + sidx(r, n3 * 16 + lx, 256)] = f2b(part[n3]);
        }
    }
    __syncthreads();

    // ================= phase N =================
    // fo1 -> BIG [256][128], cols: 0..63 = ebar part (fo1[48..111]), 64..111 = xn part
    for (int i = t; i < 32768; i += 256) {
        int ch = i >> 7, k = i & 127;
        float v = 0.f;
        if (k < 64)       v = fo1_w[ch * 112 + PP + k];
        else if (k < 112) v = fo1_w[ch * 112 + (k - 64)];
        L[BIGO + sidx(ch, k, 128)] = f2b(v);
    }
    __syncthreads();

    // L1N: M=256, N=64 nodes, K=128 (ks 0,1 from ebar in S1RO; ks 2,3 from XNTO)
    {
        f32x4 accN[4][4];
#pragma unroll
        for (int j = 0; j < 4; ++j)
#pragma unroll
            for (int nt = 0; nt < 4; ++nt) accN[j][nt] = (f32x4){0.f,0.f,0.f,0.f};
#pragma unroll
        for (int ks = 0; ks < 4; ++ks) {
            bf16x8 Bf[4];
#pragma unroll
            for (int nt = 0; nt < 4; ++nt)
                Bf[nt] = (ks < 2) ? ldfrag(L + S1RO, nt * 16 + lx, ks * 32 + lq * 8, 256)
                                  : ldfrag(L + XNTO, nt * 16 + lx, (ks - 2) * 32 + lq * 8, 64);
#pragma unroll
            for (int j = 0; j < 4; ++j) {
                bf16x8 Af = ldfrag(L + BIGO, (4 * w + j) * 16 + lx, ks * 32 + lq * 8, 128);
#pragma unroll
                for (int nt = 0; nt < 4; ++nt) accN[j][nt] = MFMA(Af, Bf[nt], accN[j][nt]);
            }
        }
        __syncthreads();   // BIG/S1RO/XNTO reads done; restage below
#pragma unroll
        for (int j = 0; j < 4; ++j) {
            int ch0 = (4 * w + j) * 16 + lq * 4;
            float4 bi = *(const float4*)(fo1_b + ch0);
#pragma unroll
            for (int nt = 0; nt < 4; ++nt)
                stAct(L + S1SO, nt * 16 + lx, ch0, 256, accN[j][nt], bi);
        }
    }
    // fo2 -> BIG [128][256]; fo3 -> S1RO [64][128]
    for (int i = t; i < 16384; i += 256) {
        int ch = i >> 7, k2 = (i & 127) * 2;
        float2 v = *(const float2*)(fo2_w + ch * 256 + k2);
        *(unsigned*)(L + BIGO + sidx(ch, k2, 256)) = pku(v.x, v.y);
    }
    for (int i = t; i < 4096; i += 256) {
        int ch = i >> 6, k2 = (i & 63) * 2;
        float2 v = *(const float2*)(fo3_w + ch * 128 + k2);
        *(unsigned*)(L + S1RO + sidx(ch, k2, 128)) = pku(v.x, v.y);
    }
    __syncthreads();

    // L2N: M=128, N=64, K=256 -> act2N @ A2WO [64][128]
    {
        f32x4 a2N[2][4];
#pragma unroll
        for (int j = 0; j < 2; ++j)
#pragma unroll
            for (int nt = 0; nt < 4; ++nt) a2N[j][nt] = (f32x4){0.f,0.f,0.f,0.f};
#pragma unroll
        for (int ks = 0; ks < 8; ++ks) {
            bf16x8 Bf[4];
#pragma unroll
            for (int nt = 0; nt < 4; ++nt) Bf[nt] = ldfrag(L + S1SO, nt * 16 + lx, ks * 32 + lq * 8, 256);
#pragma unroll
            for (int j = 0; j < 2; ++j) {
                bf16x8 Af = ldfrag(L + BIGO, (2 * w + j) * 16 + lx, ks * 32 + lq * 8, 256);
#pragma unroll
                for (int nt = 0; nt < 4; ++nt) a2N[j][nt] = MFMA(Af, Bf[nt], a2N[j][nt]);
            }
        }
#pragma unroll
        for (int j = 0; j < 2; ++j) {
            int ch0 = (2 * w + j) * 16 + lq * 4;
            float4 bi = *(const float4*)(fo2_b + ch0);
#pragma unroll
            for (int nt = 0; nt < 4; ++nt)
                stAct(L + A2WO, nt * 16 + lx, ch0, 128, a2N[j][nt], bi);
        }
    }
    __syncthreads();

    // L3N: M=64 (fo3 ch), N=64 nodes, K=128; relu+bias, sum over nodes
    {
        f32x4 a3N[4];
#pragma unroll
        for (int nt = 0; nt < 4; ++nt) a3N[nt] = (f32x4){0.f,0.f,0.f,0.f};
#pragma unroll
        for (int ks3 = 0; ks3 < 4; ++ks3) {
            bf16x8 Af = ldfrag(L + S1RO, 16 * w + lx, ks3 * 32 + lq * 8, 128);
#pragma unroll
            for (int nt = 0; nt < 4; ++nt) {
                bf16x8 Bf = ldfrag(L + A2WO, nt * 16 + lx, ks3 * 32 + lq * 8, 128);
                a3N[nt] = MFMA(Af, Bf, a3N[nt]);
            }
        }
        float4 b3 = *(const float4*)(fo3_b + 16 * w + lq * 4);
        float o0 = 0.f, o1 = 0.f, o2 = 0.f, o3 = 0.f;
#pragma unroll
        for (int nt = 0; nt < 4; ++nt) {
            o0 += fmaxf(a3N[nt][0] + b3.x, 0.f);
            o1 += fmaxf(a3N[nt][1] + b3.y, 0.f);
            o2 += fmaxf(a3N[nt][2] + b3.z, 0.f);
            o3 += fmaxf(a3N[nt][3] + b3.w, 0.f);
        }
#pragma unroll
        for (int off = 8; off >= 1; off >>= 1) {
            o0 += __shfl_xor(o0, off, 16);
            o1 += __shfl_xor(o1, off, 16);
            o2 += __shfl_xor(o2, off, 16);
            o3 += __shfl_xor(o3, off, 16);
        }
        if (lx == 0) {
            float* red = (float*)(L + XNTO);
            *(float4*)&red[16 * w + lq * 4] = make_float4(o0, o1, o2, o3);
        }
    }
    __syncthreads();

    // ---- final FCs (fp32)
    {
        float* red = (float*)(L + XNTO);
        float* h1  = red + 64;
        float* h2  = red + 96;
        if (t < 25) {
            float s = fc1_b[t];
            for (int k = 0; k < 64; ++k) s += fc1_w[t * 64 + k] * red[k];
            h1[t] = s;
        }
        __syncthreads();
        if (t < 15) {
            float s = fc2_b[t];
            for (int k = 0; k < 25; ++k) s += fc2_w[t * 25 + k] * h1[k];
            h2[t] = s;
        }
        __syncthreads();
        if (t < 5) {
            float s = fc3_b[t];
            for (int k = 0; k < 15; ++k) s += fc3_w[t * 15 + k] * h2[k];
            out[b * 5 + t] = s;
        }
    }
}

extern "C" void kernel_launch(void* const* d_in, const int* in_sizes, int n_in,
                              void* d_out, int out_size, void* d_ws, size_t ws_size,
                              hipStream_t stream)
{
    const float* x        = (const float*)d_in[0];
    const float* bn_gamma = (const float*)d_in[3];
    const float* bn_beta  = (const float*)d_in[4];
    const float* fr1_w = (const float*)d_in[5];
    const float* fr1_b = (const float*)d_in[6];
    const float* fr2_w = (const float*)d_in[7];
    const float* fr2_b = (const float*)d_in[8];
    const float* fr3_w = (const float*)d_in[9];
    const float* fr3_b = (const float*)d_in[10];
    const float* fo1_w = (const float*)d_in[11];
    const float* fo1_b = (const float*)d_in[12];
    const float* fo2_w = (const float*)d_in[13];
    const float* fo2_b = (const float*)d_in[14];
    const float* fo3_w = (const float*)d_in[15];
    const float* fo3_b = (const float*)d_in[16];
    const float* fc1_w = (const float*)d_in[17];
    const float* fc1_b = (const float*)d_in[18];
    const float* fc2_w = (const float*)d_in[19];
    const float* fc2_b = (const float*)d_in[20];
    const float* fc3_w = (const float*)d_in[21];
    const float* fc3_b = (const float*)d_in[22];

    float* ws    = (float*)d_ws;
    float* scale = ws;
    float* bias  = ws + 64;
    float* out   = (float*)d_out;

    bn_stats_kernel<<<dim3(PP), dim3(256), 0, stream>>>(x, bn_gamma, bn_beta, scale, bias);
    meg_kernel<<<dim3(BB), dim3(256), 0, stream>>>(
        x, scale, bias,
        fr1_w, fr1_b, fr2_w, fr2_b, fr3_w, fr3_b,
        fo1_w, fo1_b, fo2_w, fo2_b, fo3_w, fo3_b,
        fc1_w, fc1_b, fc2_w, fc2_b, fc3_w, fc3_b, out);
}

// Round 5
// 310.310 us; speedup vs baseline: 1.5240x; 1.2168x over previous
//
#include <hip/hip_runtime.h>
#include <hip/hip_bf16.h>

#define BB 256
#define PP 48
#define NN 64
#define EPSBN 1e-5f

typedef __attribute__((ext_vector_type(8))) short bf16x8;
typedef __attribute__((ext_vector_type(4))) float f32x4;

// ---- LDS regions (ushort offsets), total 81920 ushorts = 163840 B (160 KiB) ----
#define BIGO 0       // 32768: fr1R/[+16384]fr1S -> fr2 [128][256]   | N: fo1 [256][128] -> fo2 [128][256]
#define S1SO 32768   // 16384: S1S [64][256]                          | N: act1N [64][256]
#define S1RO 49152   // 16384: S1R [64][256]; cols 0..63 -> ebar      | N: fo3 [64][128] (rows 0..31 area)
#define A2WO 65536   // 16384: phase E: 8 waves x 2048 private act2   | N: act2N [64][128] @65536
#define XNT2 73728   //  4096: xnT [64][64] (prologue + phase N; clobbered by waves 4..7 a2w in phase E)
#define REDO 77824   //  4096: phase N red/h1/h2 (floats)
#define LDSE 81920

union U8 { bf16x8 v; unsigned u[4]; };

__device__ __forceinline__ unsigned pku(float a, float b) {
    union { __hip_bfloat162 h; unsigned u; } cv;
    cv.h = __float22bfloat162_rn(make_float2(a, b));
    return cv.u;
}
__device__ __forceinline__ ushort f2b(float f) {
    union { float f; unsigned u; } a; a.f = f;
    unsigned u = a.u + 0x7FFFu + ((a.u >> 16) & 1u);
    return (ushort)(u >> 16);
}
__device__ __forceinline__ float loF(unsigned u) { union { unsigned x; float f; } c; c.x = u << 16; return c.f; }
__device__ __forceinline__ float hiF(unsigned u) { union { unsigned x; float f; } c; c.x = u & 0xffff0000u; return c.f; }

__device__ __forceinline__ int sidx(int row, int k, int kpad) {
    return row * kpad + ((((k >> 3) ^ (row & 7)) << 3) | (k & 7));
}
__device__ __forceinline__ bf16x8 ldfrag(const ushort* buf, int row, int k, int kpad) {
    return *(const bf16x8*)(buf + row * kpad + (((k >> 3) ^ (row & 7)) << 3));
}
__device__ __forceinline__ f32x4 MFMA(bf16x8 a, bf16x8 b, f32x4 c) {
    return __builtin_amdgcn_mfma_f32_16x16x32_bf16(a, b, c, 0, 0, 0);
}
__device__ __forceinline__ void stAct(ushort* buf, int row, int c0, int kpad, f32x4 a, float4 bi) {
    uint2 o;
    o.x = pku(fmaxf(a[0] + bi.x, 0.f), fmaxf(a[1] + bi.y, 0.f));
    o.y = pku(fmaxf(a[2] + bi.z, 0.f), fmaxf(a[3] + bi.w, 0.f));
    *(uint2*)(buf + row * kpad + ((((c0 >> 3) ^ (row & 7)) << 3) | (c0 & 7))) = o;
}
__device__ __forceinline__ void stRaw(ushort* buf, int row, int c0, int kpad, f32x4 a, float4 bi) {
    uint2 o;
    o.x = pku(a[0] + bi.x, a[1] + bi.y);
    o.y = pku(a[2] + bi.z, a[3] + bi.w);
    *(uint2*)(buf + row * kpad + ((((c0 >> 3) ^ (row & 7)) << 3) | (c0 & 7))) = o;
}

// ---------------- batchnorm stats ----------------
__global__ __launch_bounds__(256) void bn_stats_kernel(
    const float* __restrict__ x, const float* __restrict__ gamma,
    const float* __restrict__ beta, float* __restrict__ scale, float* __restrict__ bias)
{
    __shared__ float s_sum[256], s_sq[256];
    int p = blockIdx.x, t = threadIdx.x;
    float sum = 0.f, sq = 0.f;
    for (int i = t; i < BB * NN; i += 256) {
        int b = i >> 6, n = i & 63;
        float v = x[b * PP * NN + p * NN + n];
        sum += v; sq += v * v;
    }
    s_sum[t] = sum; s_sq[t] = sq;
    __syncthreads();
    for (int off = 128; off > 0; off >>= 1) {
        if (t < off) { s_sum[t] += s_sum[t + off]; s_sq[t] += s_sq[t + off]; }
        __syncthreads();
    }
    if (t == 0) {
        float inv = 1.f / (float)(BB * NN);
        float mean = s_sum[0] * inv;
        float var  = s_sq[0] * inv - mean * mean;
        float sc   = gamma[p] * rsqrtf(var + EPSBN);
        scale[p] = sc;
        bias[p]  = beta[p] - mean * sc;
    }
}

// ---------------- mega kernel: one block per batch, 8 waves ----------------
__global__ __launch_bounds__(512, 2) void meg_kernel(
    const float* __restrict__ x,
    const float* __restrict__ scl, const float* __restrict__ bia,
    const float* __restrict__ fr1_w, const float* __restrict__ fr1_b,
    const float* __restrict__ fr2_w, const float* __restrict__ fr2_b,
    const float* __restrict__ fr3_w, const float* __restrict__ fr3_b,
    const float* __restrict__ fo1_w, const float* __restrict__ fo1_b,
    const float* __restrict__ fo2_w, const float* __restrict__ fo2_b,
    const float* __restrict__ fo3_w, const float* __restrict__ fo3_b,
    const float* __restrict__ fc1_w, const float* __restrict__ fc1_b,
    const float* __restrict__ fc2_w, const float* __restrict__ fc2_b,
    const float* __restrict__ fc3_w, const float* __restrict__ fc3_b,
    float* __restrict__ out)
{
    __shared__ __align__(16) ushort L[LDSE];

    int b = blockIdx.x, t = threadIdx.x;
    int w = t >> 6, l = t & 63, lx = l & 15, lq = l >> 4;

    // ---- xnT [64][64] (cols 48..63 zero)
    for (int i = t; i < 4096; i += 512) {
        int n = i >> 6, k = i & 63;
        float v = (k < PP) ? x[b * PP * NN + k * NN + n] * scl[k] + bia[k] : 0.f;
        L[XNT2 + sidx(n, k, 64)] = f2b(v);
    }
    // ---- fr1 receiver / sender halves into BIG
    for (int i = t; i < 16384; i += 512) {
        int ch = i >> 6, k = i & 63;
        L[BIGO + sidx(ch, k, 64)]         = f2b((k < PP) ? fr1_w[ch * 96 + k] : 0.f);
        L[BIGO + 16384 + sidx(ch, k, 64)] = f2b((k < PP) ? fr1_w[ch * 96 + PP + k] : 0.f);
    }
    __syncthreads();

    // ---- GEMM1+2 fused: S1R = fr1R.xn + b1, S1S = fr1S.xn  (each wave: 2 m-tiles)
    {
        f32x4 aR[2][4], aS[2][4];
#pragma unroll
        for (int j = 0; j < 2; ++j)
#pragma unroll
            for (int nt = 0; nt < 4; ++nt) { aR[j][nt] = (f32x4){0.f,0.f,0.f,0.f}; aS[j][nt] = (f32x4){0.f,0.f,0.f,0.f}; }
#pragma unroll
        for (int ks = 0; ks < 2; ++ks) {
            bf16x8 Bf[4];
#pragma unroll
            for (int nt = 0; nt < 4; ++nt) Bf[nt] = ldfrag(L + XNT2, nt * 16 + lx, ks * 32 + lq * 8, 64);
#pragma unroll
            for (int j = 0; j < 2; ++j) {
                bf16x8 AfR = ldfrag(L + BIGO,         (2 * w + j) * 16 + lx, ks * 32 + lq * 8, 64);
                bf16x8 AfS = ldfrag(L + BIGO + 16384, (2 * w + j) * 16 + lx, ks * 32 + lq * 8, 64);
#pragma unroll
                for (int nt = 0; nt < 4; ++nt) {
                    aR[j][nt] = MFMA(AfR, Bf[nt], aR[j][nt]);
                    aS[j][nt] = MFMA(AfS, Bf[nt], aS[j][nt]);
                }
            }
        }
        __syncthreads();   // BIG reads done; restage fr2 below
#pragma unroll
        for (int j = 0; j < 2; ++j) {
            int ch0 = (2 * w + j) * 16 + lq * 4;
            float4 bi = *(const float4*)(fr1_b + ch0);
            float4 zb = make_float4(0.f, 0.f, 0.f, 0.f);
#pragma unroll
            for (int nt = 0; nt < 4; ++nt) {
                stRaw(L + S1RO, nt * 16 + lx, ch0, 256, aR[j][nt], bi);
                stRaw(L + S1SO, nt * 16 + lx, ch0, 256, aS[j][nt], zb);
            }
        }
    }
    // ---- fr2 [128][256] -> BIG
    for (int i = t; i < 16384; i += 512) {
        int ch = i >> 7, k2 = (i & 127) * 2;
        float2 v = *(const float2*)(fr2_w + ch * 256 + k2);
        *(unsigned*)(L + BIGO + sidx(ch, k2, 256)) = pku(v.x, v.y);
    }
    // ---- hoist fr3 (B-operand of transposed L3) + biases to registers
    bf16x8 bfw[4][4];
#pragma unroll
    for (int n3 = 0; n3 < 4; ++n3)
#pragma unroll
        for (int ks3 = 0; ks3 < 4; ++ks3) {
            const float* p = fr3_w + (n3 * 16 + lx) * 128 + ks3 * 32 + lq * 8;
            float4 f0 = *(const float4*)p;
            float4 f1 = *(const float4*)(p + 4);
            U8 g;
            g.u[0] = pku(f0.x, f0.y); g.u[1] = pku(f0.z, f0.w);
            g.u[2] = pku(f1.x, f1.y); g.u[3] = pku(f1.z, f1.w);
            bfw[n3][ks3] = g.v;
        }
    float4 b2c[8];
#pragma unroll
    for (int m = 0; m < 8; ++m) b2c[m] = *(const float4*)(fr2_b + m * 16 + lq * 4);
    float b3c[4];
#pragma unroll
    for (int n3 = 0; n3 < 4; ++n3) b3c[n3] = fr3_b[n3 * 16 + lx];
    __syncthreads();

    // ================= phase E: 8 receivers per wave, zero barriers =================
    ushort* a2w = L + A2WO + w * 2048;     // wave-private [16][128]
#pragma unroll 1
    for (int i = 0; i < 8; ++i) {
        int r = w * 8 + i;
        float s1rf[64];
#pragma unroll
        for (int ks = 0; ks < 8; ++ks) {
            U8 f; f.v = ldfrag(L + S1RO, r, ks * 32 + lq * 8, 256);
#pragma unroll
            for (int jj = 0; jj < 4; ++jj) {
                s1rf[ks * 8 + 2 * jj]     = loF(f.u[jj]);
                s1rf[ks * 8 + 2 * jj + 1] = hiF(f.u[jj]);
            }
        }
        float part[4] = {0.f, 0.f, 0.f, 0.f};
#pragma unroll 1
        for (int p = 0; p < 2; ++p) {
            int eA = p * 32 + lx, eB = eA + 16;
            int sA = eA + (eA >= r);
            int sB = eB + (eB >= r); if (sB > 63) sB = 63;   // pad edge 63

            f32x4 acc2[8][2];
#pragma unroll
            for (int m = 0; m < 8; ++m) { acc2[m][0] = (f32x4){0.f,0.f,0.f,0.f}; acc2[m][1] = (f32x4){0.f,0.f,0.f,0.f}; }
#pragma unroll
            for (int ks = 0; ks < 8; ++ks) {
                U8 fa, fb;
                fa.v = ldfrag(L + S1SO, sA, ks * 32 + lq * 8, 256);
                fb.v = ldfrag(L + S1SO, sB, ks * 32 + lq * 8, 256);
                U8 bA, bB;
#pragma unroll
                for (int jj = 0; jj < 4; ++jj) {
                    float r0 = s1rf[ks * 8 + 2 * jj], r1 = s1rf[ks * 8 + 2 * jj + 1];
                    bA.u[jj] = pku(fmaxf(r0 + loF(fa.u[jj]), 0.f), fmaxf(r1 + hiF(fa.u[jj]), 0.f));
                    bB.u[jj] = pku(fmaxf(r0 + loF(fb.u[jj]), 0.f), fmaxf(r1 + hiF(fb.u[jj]), 0.f));
                }
#pragma unroll
                for (int m = 0; m < 8; ++m) {
                    bf16x8 Af = ldfrag(L + BIGO, m * 16 + lx, ks * 32 + lq * 8, 256);
                    acc2[m][0] = MFMA(Af, bA.v, acc2[m][0]);
                    acc2[m][1] = MFMA(Af, bB.v, acc2[m][1]);
                }
            }
#pragma unroll
            for (int cc = 0; cc < 2; ++cc) {
#pragma unroll
                for (int m = 0; m < 8; ++m)
                    stAct(a2w, lx, m * 16 + lq * 4, 128, acc2[m][cc], b2c[m]);
                f32x4 acc3[4];
#pragma unroll
                for (int n3 = 0; n3 < 4; ++n3) acc3[n3] = (f32x4){0.f,0.f,0.f,0.f};
#pragma unroll
                for (int ks3 = 0; ks3 < 4; ++ks3) {
                    bf16x8 af = ldfrag(a2w, lx, ks3 * 32 + lq * 8, 128);
#pragma unroll
                    for (int n3 = 0; n3 < 4; ++n3) acc3[n3] = MFMA(af, bfw[n3][ks3], acc3[n3]);
                }
                bool mpad = (p == 1) && (cc == 1) && (lq == 3);
#pragma unroll
                for (int n3 = 0; n3 < 4; ++n3) {
                    float bv = b3c[n3];
                    float s = fmaxf(acc3[n3][0] + bv, 0.f) + fmaxf(acc3[n3][1] + bv, 0.f)
                            + fmaxf(acc3[n3][2] + bv, 0.f);
                    float s3 = fmaxf(acc3[n3][3] + bv, 0.f);
                    part[n3] += s + (mpad ? 0.f : s3);
                }
            }
        }
#pragma unroll
        for (int n3 = 0; n3 < 4; ++n3) {
            part[n3] += __shfl_xor(part[n3], 16, 64);
            part[n3] += __shfl_xor(part[n3], 32, 64);
        }
        if (lq == 0) {
#pragma unroll
            for (int n3 = 0; n3 < 4; ++n3)
                L[S1RO + sidx(r, n3 * 16 + lx, 256)] = f2b(part[n3]);
        }
    }
    __syncthreads();

    // ================= phase N =================
    // fo1 -> BIG [256][128] (cols 0..63 ebar part, 64..111 xn part)
    for (int i = t; i < 32768; i += 512) {
        int ch = i >> 7, k = i & 127;
        float v = 0.f;
        if (k < 64)       v = fo1_w[ch * 112 + PP + k];
        else if (k < 112) v = fo1_w[ch * 112 + (k - 64)];
        L[BIGO + sidx(ch, k, 128)] = f2b(v);
    }
    // restage xnT (clobbered by waves 4..7 a2w in phase E)
    for (int i = t; i < 4096; i += 512) {
        int n = i >> 6, k = i & 63;
        float v = (k < PP) ? x[b * PP * NN + k * NN + n] * scl[k] + bia[k] : 0.f;
        L[XNT2 + sidx(n, k, 64)] = f2b(v);
    }
    __syncthreads();

    // L1N: M=256 (wave: 2 m-tiles), N=64 nodes, K=128 (ks 0,1 ebar from S1RO; ks 2,3 from XNT2)
    {
        f32x4 accN[2][4];
#pragma unroll
        for (int j = 0; j < 2; ++j)
#pragma unroll
            for (int nt = 0; nt < 4; ++nt) accN[j][nt] = (f32x4){0.f,0.f,0.f,0.f};
#pragma unroll
        for (int ks = 0; ks < 4; ++ks) {
            bf16x8 Bf[4];
#pragma unroll
            for (int nt = 0; nt < 4; ++nt)
                Bf[nt] = (ks < 2) ? ldfrag(L + S1RO, nt * 16 + lx, ks * 32 + lq * 8, 256)
                                  : ldfrag(L + XNT2, nt * 16 + lx, (ks - 2) * 32 + lq * 8, 64);
#pragma unroll
            for (int j = 0; j < 2; ++j) {
                bf16x8 Af = ldfrag(L + BIGO, (2 * w + j) * 16 + lx, ks * 32 + lq * 8, 128);
#pragma unroll
                for (int nt = 0; nt < 4; ++nt) accN[j][nt] = MFMA(Af, Bf[nt], accN[j][nt]);
            }
        }
        __syncthreads();   // BIG/S1RO/XNT2 reads done
#pragma unroll
        for (int j = 0; j < 2; ++j) {
            int ch0 = (2 * w + j) * 16 + lq * 4;
            float4 bi = *(const float4*)(fo1_b + ch0);
#pragma unroll
            for (int nt = 0; nt < 4; ++nt)
                stAct(L + S1SO, nt * 16 + lx, ch0, 256, accN[j][nt], bi);
        }
    }
    // fo2 -> BIG [128][256]; fo3 -> S1RO [64][128]
    for (int i = t; i < 16384; i += 512) {
        int ch = i >> 7, k2 = (i & 127) * 2;
        float2 v = *(const float2*)(fo2_w + ch * 256 + k2);
        *(unsigned*)(L + BIGO + sidx(ch, k2, 256)) = pku(v.x, v.y);
    }
    for (int i = t; i < 4096; i += 512) {
        int ch = i >> 6, k2 = (i & 63) * 2;
        float2 v = *(const float2*)(fo3_w + ch * 128 + k2);
        *(unsigned*)(L + S1RO + sidx(ch, k2, 128)) = pku(v.x, v.y);
    }
    __syncthreads();

    // L2N: M=128 (wave: m-tile w), N=64, K=256 -> act2N @ A2WO [64][128]
    {
        f32x4 a2N[4];
#pragma unroll
        for (int nt = 0; nt < 4; ++nt) a2N[nt] = (f32x4){0.f,0.f,0.f,0.f};
#pragma unroll
        for (int ks = 0; ks < 8; ++ks) {
            bf16x8 Bf[4];
#pragma unroll
            for (int nt = 0; nt < 4; ++nt) Bf[nt] = ldfrag(L + S1SO, nt * 16 + lx, ks * 32 + lq * 8, 256);
            bf16x8 Af = ldfrag(L + BIGO, w * 16 + lx, ks * 32 + lq * 8, 256);
#pragma unroll
            for (int nt = 0; nt < 4; ++nt) a2N[nt] = MFMA(Af, Bf[nt], a2N[nt]);
        }
        int ch0 = w * 16 + lq * 4;
        float4 bi = *(const float4*)(fo2_b + ch0);
#pragma unroll
        for (int nt = 0; nt < 4; ++nt)
            stAct(L + A2WO, nt * 16 + lx, ch0, 128, a2N[nt], bi);
    }
    __syncthreads();

    // L3N: M=64 (fo3 ch), N=64 nodes, K=128 (waves 0..3); relu+bias, sum over nodes
    if (w < 4) {
        f32x4 a3N[4];
#pragma unroll
        for (int nt = 0; nt < 4; ++nt) a3N[nt] = (f32x4){0.f,0.f,0.f,0.f};
#pragma unroll
        for (int ks3 = 0; ks3 < 4; ++ks3) {
            bf16x8 Af = ldfrag(L + S1RO, 16 * w + lx, ks3 * 32 + lq * 8, 128);
#pragma unroll
            for (int nt = 0; nt < 4; ++nt) {
                bf16x8 Bf = ldfrag(L + A2WO, nt * 16 + lx, ks3 * 32 + lq * 8, 128);
                a3N[nt] = MFMA(Af, Bf, a3N[nt]);
            }
        }
        float4 b3 = *(const float4*)(fo3_b + 16 * w + lq * 4);
        float o0 = 0.f, o1 = 0.f, o2 = 0.f, o3 = 0.f;
#pragma unroll
        for (int nt = 0; nt < 4; ++nt) {
            o0 += fmaxf(a3N[nt][0] + b3.x, 0.f);
            o1 += fmaxf(a3N[nt][1] + b3.y, 0.f);
            o2 += fmaxf(a3N[nt][2] + b3.z, 0.f);
            o3 += fmaxf(a3N[nt][3] + b3.w, 0.f);
        }
#pragma unroll
        for (int off = 8; off >= 1; off >>= 1) {
            o0 += __shfl_xor(o0, off, 16);
            o1 += __shfl_xor(o1, off, 16);
            o2 += __shfl_xor(o2, off, 16);
            o3 += __shfl_xor(o3, off, 16);
        }
        if (lx == 0) {
            float* red = (float*)(L + REDO);
            *(float4*)&red[16 * w + lq * 4] = make_float4(o0, o1, o2, o3);
        }
    }
    __syncthreads();

    // ---- final FCs (fp32)
    {
        float* red = (float*)(L + REDO);
        float* h1  = red + 64;
        float* h2  = red + 96;
        if (t < 25) {
            float s = fc1_b[t];
            for (int k = 0; k < 64; ++k) s += fc1_w[t * 64 + k] * red[k];
            h1[t] = s;
        }
        __syncthreads();
        if (t < 15) {
            float s = fc2_b[t];
            for (int k = 0; k < 25; ++k) s += fc2_w[t * 25 + k] * h1[k];
            h2[t] = s;
        }
        __syncthreads();
        if (t < 5) {
            float s = fc3_b[t];
            for (int k = 0; k < 15; ++k) s += fc3_w[t * 15 + k] * h2[k];
            out[b * 5 + t] = s;
        }
    }
}

extern "C" void kernel_launch(void* const* d_in, const int* in_sizes, int n_in,
                              void* d_out, int out_size, void* d_ws, size_t ws_size,
                              hipStream_t stream)
{
    const float* x        = (const float*)d_in[0];
    const float* bn_gamma = (const float*)d_in[3];
    const float* bn_beta  = (const float*)d_in[4];
    const float* fr1_w = (const float*)d_in[5];
    const float* fr1_b = (const float*)d_in[6];
    const float* fr2_w = (const float*)d_in[7];
    const float* fr2_b = (const float*)d_in[8];
    const float* fr3_w = (const float*)d_in[9];
    const float* fr3_b = (const float*)d_in[10];
    const float* fo1_w = (const float*)d_in[11];
    const float* fo1_b = (const float*)d_in[12];
    const float* fo2_w = (const float*)d_in[13];
    const float* fo2_b = (const float*)d_in[14];
    const float* fo3_w = (const float*)d_in[15];
    const float* fo3_b = (const float*)d_in[16];
    const float* fc1_w = (const float*)d_in[17];
    const float* fc1_b = (const float*)d_in[18];
    const float* fc2_w = (const float*)d_in[19];
    const float* fc2_b = (const float*)d_in[20];
    const float* fc3_w = (const float*)d_in[21];
    const float* fc3_b = (const float*)d_in[22];

    float* ws    = (float*)d_ws;
    float* scale = ws;
    float* bias  = ws + 64;
    float* out   = (float*)d_out;

    bn_stats_kernel<<<dim3(PP), dim3(256), 0, stream>>>(x, bn_gamma, bn_beta, scale, bias);
    meg_kernel<<<dim3(BB), dim3(512), 0, stream>>>(
        x, scale, bias,
        fr1_w, fr1_b, fr2_w, fr2_b, fr3_w, fr3_b,
        fo1_w, fo1_b, fo2_w, fo2_b, fo3_w, fo3_b,
        fc1_w, fc1_b, fc2_w, fc2_b, fc3_w, fc3_b, out);
}